// Round 9
// baseline (122.378 us; speedup 1.0000x reference)
//
#include <hip/hip_runtime.h>

// Varlen causal GQA prefill attention, B=4 S=2048 Hq=16 Hkv=4 D=128 (fp32 io).
// R9: (1) fragment-ordered K/V images: each MFMA fragment chunk (1KB = 64
// lanes x 16B) stored contiguous, so every ds_read is base+lane*16 with a
// compile-time offset:N immediate — zero address VALU, zero bank conflicts,
// no XOR swizzle. (2) counted-vmcnt pipeline (T4): STAGE(t+1); vmcnt(8);
// s_barrier; compute(t); s_barrier — prefetch loads stay in flight across
// barriers, no vmcnt(0) drain in the main loop.
// Keeps: 32x32x16 MFMA, swapped QK^T, exp2-domain softmax, in-register P via
// cvt_pk+permlane32_swap, defer-max, tree reductions, heavy-first queue.

typedef __attribute__((ext_vector_type(8))) short bs8;       // 8 bf16 (4 VGPR)
typedef __attribute__((ext_vector_type(16))) float f16x;     // 32x32 acc
typedef __attribute__((ext_vector_type(4))) unsigned int u32x4;
typedef __attribute__((ext_vector_type(4))) unsigned short u16x4;
typedef unsigned short u16;
typedef unsigned int u32;

#define B_ 4
#define S_ 2048
#define HQ_ 16
#define HKV_ 4
#define NQT 16        // q-tiles of 128
#define NKT_TOT 32    // kv-tiles of 64
#define TILE_ELEMS 8192  // 16 chunks x 512 elems = 16KB per tile image

__device__ __forceinline__ u16 f2bf(float f) {  // fp32 -> bf16 RNE
  u32 u = __float_as_uint(f);
  u += 0x7fffu + ((u >> 16) & 1u);
  return (u16)(u >> 16);
}

// ---- pre-pass 1: K -> fragment-ordered bf16 images.
// chunk c = kb*8+ki (0..15); lane l: K[kv = kb*32+(l&31)][d = ki*16+(l>>5)*8 ..+8]
// stored at tile_base + c*512 + l*8 (elems).
__global__ void pack_k(const float* __restrict__ k, u16* __restrict__ kp) {
  int ti = blockIdx.x;                 // (b*HKV+h)*32 + kt
  int kt = ti & 31;
  int bh = ti >> 5;
  int h = bh & 3, b = bh >> 2;
#pragma unroll
  for (int p = 0; p < 4; ++p) {
    int s = p * 256 + threadIdx.x;     // slot 0..1023
    int c = s >> 6, l = s & 63;
    int kb = c >> 3, ki = c & 7;
    int kv = kb * 32 + (l & 31);
    int d0 = ki * 16 + (l >> 5) * 8;
    const float* src = k + (size_t)(b * S_ + kt * 64 + kv) * 512 + h * 128 + d0;
    float4 a = *(const float4*)src;
    float4 cc = *(const float4*)(src + 4);
    u16* dst = kp + (size_t)ti * TILE_ELEMS + s * 8;
    u16x4 lo, hi2;
    lo.x = f2bf(a.x); lo.y = f2bf(a.y); lo.z = f2bf(a.z); lo.w = f2bf(a.w);
    hi2.x = f2bf(cc.x); hi2.y = f2bf(cc.y); hi2.z = f2bf(cc.z); hi2.w = f2bf(cc.w);
    *(u16x4*)dst = lo;
    *(u16x4*)(dst + 4) = hi2;
  }
}

// ---- pre-pass 2: V -> fragment-ordered bf16 images (PV B-operand).
// chunk c = dt*4+kb*2+ks; lane l: V[kv = kb*32+ks*16+(l>>5)*8 ..+8][d = dt*32+(l&31)]
__global__ void pack_v(const float* __restrict__ v, u16* __restrict__ vp) {
  int ti = blockIdx.x;
  int kt = ti & 31;
  int bh = ti >> 5;
  int h = bh & 3, b = bh >> 2;
#pragma unroll
  for (int p = 0; p < 4; ++p) {
    int s = p * 256 + threadIdx.x;
    int c = s >> 6, l = s & 63;
    int dt = c >> 2, kb = (c >> 1) & 1, ks = c & 1;
    int d = dt * 32 + (l & 31);
    int kv0 = kb * 32 + ks * 16 + (l >> 5) * 8;
    const float* src = v + (size_t)(b * S_ + kt * 64 + kv0) * 512 + h * 128 + d;
    u16x4 lo, hi2;
    lo.x = f2bf(src[0]);          lo.y = f2bf(src[512]);
    lo.z = f2bf(src[1024]);       lo.w = f2bf(src[1536]);
    hi2.x = f2bf(src[2048]);      hi2.y = f2bf(src[2560]);
    hi2.z = f2bf(src[3072]);      hi2.w = f2bf(src[3584]);
    u16* dst = vp + (size_t)ti * TILE_ELEMS + s * 8;
    *(u16x4*)dst = lo;
    *(u16x4*)(dst + 4) = hi2;
  }
}

// ---- main flash attention ---------------------------------------------------
__device__ __forceinline__ void gl2lds(const u16* g, u16* l) {
  __builtin_amdgcn_global_load_lds((const __attribute__((address_space(1))) void*)g,
                                   (__attribute__((address_space(3))) void*)l,
                                   16, 0, 0);
}

// __launch_bounds__ rule on this toolchain: VGPR cap = 256 / (2nd arg).
__global__ __launch_bounds__(256, 2) void attn_fwd(
    const float* __restrict__ q, const u16* __restrict__ kp,
    const u16* __restrict__ vp, float* __restrict__ out) {
  // [slot 0 | slot 1], each slot = [K 8192 elems | V 8192 elems]; 64KB total.
  __shared__ u16 Sh[2 * 2 * TILE_ELEMS];

  const int bx = blockIdx.x;
  const int qt = (NQT - 1) - (bx >> 6);   // heavy q-tiles first (queue balance)
  const int bh = bx & 63;
  const int b = bh >> 4, hq = bh & 15, hkv = hq >> 2;
  const int w = threadIdx.x >> 6, lane = threadIdx.x & 63;
  const int l31 = lane & 31, hi = lane >> 5;
  const int q0 = qt * 128;
  const float scale2 = 0.08838834764831845f * 1.4426950408889634f;  // /sqrt(D)*log2(e)

  // Q B-frags in registers: qf[ki] = Q[q=l31][ki*16 + hi*8 + 0..7] * scale2
  bs8 qf[8];
  {
    int row = b * S_ + q0 + w * 32 + l31;
    const float* qrow = q + (size_t)row * 2048 + hq * 128;
#pragma unroll
    for (int ki = 0; ki < 8; ++ki) {
      const float* p0 = qrow + ki * 16 + hi * 8;
      float4 a = *(const float4*)p0;
      float4 c = *(const float4*)(p0 + 4);
      bs8 f;
      f[0] = (short)f2bf(a.x * scale2); f[1] = (short)f2bf(a.y * scale2);
      f[2] = (short)f2bf(a.z * scale2); f[3] = (short)f2bf(a.w * scale2);
      f[4] = (short)f2bf(c.x * scale2); f[5] = (short)f2bf(c.y * scale2);
      f[6] = (short)f2bf(c.z * scale2); f[7] = (short)f2bf(c.w * scale2);
      qf[ki] = f;
    }
  }

  f16x O[4];
#pragma unroll
  for (int dt = 0; dt < 4; ++dt)
#pragma unroll
    for (int e = 0; e < 16; ++e) O[dt][e] = 0.f;
  float m_run = -1e30f, l_run = 0.f;   // log2-domain

  const size_t tbase = (size_t)((b * HKV_ + hkv) * NKT_TOT) * TILE_ELEMS;
  const u16* kbase = kp + tbase;
  const u16* vbase = vp + tbase;
  const int nkt = 2 * qt + 2;
  const int myrowmax = q0 + w * 32 + 31;
  const int qpos = q0 + w * 32 + l31;

  // per-wave staging: wave w stages chunks [w*4, w*4+4) of K and of V.
#define STAGE(t_, slot_)                                                     \
  {                                                                          \
    const u16* kg_ = kbase + (size_t)(t_) * TILE_ELEMS;                      \
    const u16* vg_ = vbase + (size_t)(t_) * TILE_ELEMS;                      \
    _Pragma("unroll") for (int j = 0; j < 4; ++j) {                          \
      int c_ = w * 4 + j;                                                    \
      gl2lds(kg_ + c_ * 512 + lane * 8, &Sh[(slot_) * 16384 + c_ * 512]);    \
      gl2lds(vg_ + c_ * 512 + lane * 8, &Sh[(slot_) * 16384 + 8192 + c_ * 512]); \
    }                                                                        \
  }

  STAGE(0, 0);  // prologue: tile 0 in flight (8 loads)

  for (int t = 0; t < nkt; ++t) {
    if (t + 1 < nkt) {
      STAGE(t + 1, (t + 1) & 1);                       // 8 more in flight
      asm volatile("s_waitcnt vmcnt(8)" ::: "memory");  // tile-t loads landed
    } else {
      asm volatile("s_waitcnt vmcnt(0)" ::: "memory");
    }
    __builtin_amdgcn_s_barrier();   // all waves' tile-t data visible

    if (t * 64 <= myrowmax) {  // wave-level causal tile skip (barriers outside)
      // per-lane LDS base for this tile's slot; all reads use offset:N imm.
      const char* lbase = (const char*)Sh + ((t & 1) << 15) + (size_t)lane * 16;

      // ---- QK^T swapped: S[kv][q], col=lane&31=q ----
      f16x Sa[2];
#pragma unroll
      for (int kb = 0; kb < 2; ++kb)
#pragma unroll
        for (int e = 0; e < 16; ++e) Sa[kb][e] = 0.f;

      __builtin_amdgcn_s_setprio(1);
#pragma unroll
      for (int ki = 0; ki < 8; ++ki) {
#pragma unroll
        for (int kb = 0; kb < 2; ++kb) {
          bs8 kf = *(const bs8*)(lbase + (kb * 8 + ki) * 1024);
          Sa[kb] = __builtin_amdgcn_mfma_f32_32x32x16_bf16(kf, qf[ki], Sa[kb], 0, 0, 0);
        }
      }
      __builtin_amdgcn_s_setprio(0);

      // ---- causal mask (only the last two tiles straddle the diagonal) ----
      if (t >= 2 * qt) {
#pragma unroll
        for (int kb = 0; kb < 2; ++kb)
#pragma unroll
          for (int r = 0; r < 16; ++r) {
            int kvpos = t * 64 + kb * 32 + (r & 3) + 8 * (r >> 2) + 4 * hi;
            if (kvpos > qpos) Sa[kb][r] = -1e30f;
          }
      }

      // ---- pmax: pairwise tree (short dep chain) ----
      float tm[8];
#pragma unroll
      for (int r = 0; r < 8; ++r)
        tm[r] = fmaxf(fmaxf(Sa[0][r], Sa[0][r + 8]), fmaxf(Sa[1][r], Sa[1][r + 8]));
#pragma unroll
      for (int s = 4; s > 0; s >>= 1)
#pragma unroll
        for (int r = 0; r < s; ++r) tm[r] = fmaxf(tm[r], tm[r + s]);
      float pmax = fmaxf(tm[0], __shfl_xor(tm[0], 32, 64));

      if (__any(pmax > m_run + 8.0f)) {  // defer-max
        float mnew = fmaxf(m_run, pmax);
        float alpha = exp2f(m_run - mnew);
        m_run = mnew;
        l_run *= alpha;
#pragma unroll
        for (int r = 0; r < 16; ++r) {
          float ar = __shfl(alpha, (r & 3) + 8 * (r >> 2) + 4 * hi, 64);
#pragma unroll
          for (int dt = 0; dt < 4; ++dt) O[dt][r] *= ar;
        }
      }

      // ---- exp2 + psum tree ----
#pragma unroll
      for (int kb = 0; kb < 2; ++kb)
#pragma unroll
        for (int r = 0; r < 16; ++r) Sa[kb][r] = exp2f(Sa[kb][r] - m_run);
      float ts[8];
#pragma unroll
      for (int r = 0; r < 8; ++r)
        ts[r] = (Sa[0][r] + Sa[0][r + 8]) + (Sa[1][r] + Sa[1][r + 8]);
#pragma unroll
      for (int s = 4; s > 0; s >>= 1)
#pragma unroll
        for (int r = 0; r < s; ++r) ts[r] += ts[r + s];
      l_run += ts[0];

      // ---- P f32 -> bf16 A-frags: cvt_pk + permlane32_swap (T12) ----
      bs8 pf[2][2];
#pragma unroll
      for (int kb = 0; kb < 2; ++kb) {
        u32 pk_[8];
#pragma unroll
        for (int j = 0; j < 8; ++j) {
          float lo = Sa[kb][2 * j], hif = Sa[kb][2 * j + 1];
          asm("v_cvt_pk_bf16_f32 %0, %1, %2" : "=v"(pk_[j]) : "v"(lo), "v"(hif));
        }
#pragma unroll
        for (int ks = 0; ks < 2; ++ks) {
          auto s0 = __builtin_amdgcn_permlane32_swap((int)pk_[4 * ks], (int)pk_[4 * ks + 2], false, false);
          auto s1 = __builtin_amdgcn_permlane32_swap((int)pk_[4 * ks + 1], (int)pk_[4 * ks + 3], false, false);
          u32x4 fw;
          fw[0] = (u32)s0[0]; fw[1] = (u32)s1[0]; fw[2] = (u32)s0[1]; fw[3] = (u32)s1[1];
          pf[kb][ks] = __builtin_bit_cast(bs8, fw);
        }
      }

      // ---- PV: O[q][d] += P[q][kv] * V[kv][d], col=lane&31=d ----
      __builtin_amdgcn_s_setprio(1);
#pragma unroll
      for (int dt = 0; dt < 4; ++dt) {
#pragma unroll
        for (int kb = 0; kb < 2; ++kb)
#pragma unroll
          for (int ks = 0; ks < 2; ++ks) {
            bs8 vb = *(const bs8*)(lbase + 16384 + (dt * 4 + kb * 2 + ks) * 1024);
            O[dt] = __builtin_amdgcn_mfma_f32_32x32x16_bf16(pf[kb][ks], vb, O[dt], 0, 0, 0);
          }
      }
      __builtin_amdgcn_s_setprio(0);
    }

    __builtin_amdgcn_s_barrier();   // all reads of slot t&1 done before reuse
  }

  // ---- epilogue: combine l halves, normalize, coalesced store ----
  float lt = l_run + __shfl_xor(l_run, 32, 64);
  float inv = 1.0f / lt;
  const int orow0 = b * S_ + q0 + w * 32;
#pragma unroll
  for (int r = 0; r < 16; ++r) {
    int qr = (r & 3) + 8 * (r >> 2) + 4 * hi;
    float li = __shfl(inv, qr, 64);
    float* op = out + (size_t)(orow0 + qr) * 2048 + hq * 128 + l31;
#pragma unroll
    for (int dt = 0; dt < 4; ++dt) op[dt * 32] = O[dt][r] * li;
  }
}

extern "C" void kernel_launch(void* const* d_in, const int* in_sizes, int n_in,
                              void* d_out, int out_size, void* d_ws, size_t ws_size,
                              hipStream_t stream) {
  const float* q = (const float*)d_in[0];
  const float* k = (const float*)d_in[1];
  const float* v = (const float*)d_in[2];
  float* out = (float*)d_out;
  u16* kp = (u16*)d_ws;                                       // 8 MB K images
  u16* vp = kp + (size_t)B_ * HKV_ * NKT_TOT * TILE_ELEMS;    // 8 MB V images

  pack_k<<<B_ * HKV_ * NKT_TOT, 256, 0, stream>>>(k, kp);
  pack_v<<<B_ * HKV_ * NKT_TOT, 256, 0, stream>>>(v, vp);
  attn_fwd<<<B_ * HQ_ * NQT, 256, 0, stream>>>(q, kp, vp, out);
}